// Round 7
// baseline (124.554 us; speedup 1.0000x reference)
//
#include <hip/hip_runtime.h>

// Problem: x [64,1,257,257] f32, conv_w [1,1,2,2], conv_b [1], qparams [2,4].
// Output [64,2,256,256] f32 = concat(conv-relu, qmap) on channel axis.
//
// Analytic collapse (re-derived R2; harness-verified, absmax 0.0625):
//   - qparams provably irrelevant; qmap per patch = cos(TL)*cos(TR)*cos(BR).
//
// Measurement state (R4-R7): score ~79-80 us REGARDLESS of kernel structure
// (R2 amplified loads == R5/R7 clean LDS staging). Kernel never in top-5
// (all 256 MiB poison fills, 43-47 us) => kernel dur < 43 us, score includes
// harness fill+restores. Kernel true dur in [8.5, 43] — too wide to act on.
//
// R8 (THIS ROUND IS A DIAGNOSTIC, not a score attempt):
//   Keep R7 kernel byte-identical, then append reps = ws_size/out_bytes (=8,
//   ws is exactly 256 MiB = 8x out) replica writes of the computed outputs
//   into d_ws (nt stores, ~268 MB extra HBM writes, ~43 us). This pushes our
//   kernel above the fills' 47 us top-5 threshold so we finally read ITS row:
//   base = row_dur - extra_bytes/row_BW. M2 (base~12) -> row ~50-56;
//   M1 (base~36) -> row ~75-85. Next round reverts to R7 and acts on this.

#define BATCH 64
#define INH   257
#define INW   257
#define OH    256
#define OW    256
#define RG    32            // row-groups per image: 8 output rows each
#define LROWS 9             // input rows staged per block
#define LPITCH 264          // LDS row pitch in floats (multiple of 4, padded)
#define OUTFLOATS ((size_t)BATCH * 2 * OH * OW)   // 8,388,608

typedef float fvec4 __attribute__((ext_vector_type(4)));

__device__ __forceinline__ void store_nt4(float* p, float x, float y, float z, float w)
{
    fvec4 v; v.x = x; v.y = y; v.z = z; v.w = w;
    __builtin_nontemporal_store(v, (fvec4*)p);
}

__global__ __launch_bounds__(256) void conv_enh_diag(
    const float* __restrict__ x,
    const float* __restrict__ cw,
    const float* __restrict__ cb,
    float* __restrict__ out,
    float* __restrict__ ws,
    int reps)
{
    __shared__ float lds[LROWS * LPITCH];   // 9*264*4 = 9504 B

    const int tid = threadIdx.x;
    const int blk = blockIdx.x;
    const int rg  = blk & (RG - 1);          // 0..31 -> input rows 8*rg .. 8*rg+8
    const int b   = blk >> 5;                // 0..63

    // uniform weight/bias loads issued first: latency hides under staging
    const float w00 = cw[0], w01 = cw[1], w10 = cw[2], w11 = cw[3];
    const float bias = cb[0];

    const int r_base = rg * 8;
    const float* __restrict__ src =
        x + (size_t)b * INH * INW + (size_t)r_base * INW;

    // ---- stage: 9 rows x 257 cols; 9 coalesced row loads + 1 halo load ----
    #pragma unroll
    for (int r = 0; r < LROWS; ++r)
        lds[r * LPITCH + tid] = src[r * INW + tid];
    if (tid < LROWS)
        lds[tid * LPITCH + 256] = src[tid * INW + 256];
    __syncthreads();

    // one wave = one output row-pair across the full width
    const int j  = tid & 63;                 // 0..63 -> output cols 4j..4j+3
    const int il = tid >> 6;                 // 0..3  -> local row-pair
    const int c0 = 4 * j;

    const float* __restrict__ l0 = &lds[(2 * il) * LPITCH + c0]; // 16B-aligned
    const float* __restrict__ l1 = l0 + LPITCH;
    const float* __restrict__ l2 = l1 + LPITCH;

    const fvec4 A = *(const fvec4*)l0;  const float a4 = l0[4];
    const fvec4 M = *(const fvec4*)l1;  const float m4 = l1[4];
    const fvec4 Z = *(const fvec4*)l2;  const float z4 = l2[4];

    // cross-correlation + bias + ReLU; top row (r0) and bottom row (r0+1)
    const float t0 = fmaxf(fmaf(w11, M.y, fmaf(w10, M.x, fmaf(w01, A.y, fmaf(w00, A.x, bias)))), 0.f);
    const float t1 = fmaxf(fmaf(w11, M.z, fmaf(w10, M.y, fmaf(w01, A.z, fmaf(w00, A.y, bias)))), 0.f);
    const float t2 = fmaxf(fmaf(w11, M.w, fmaf(w10, M.z, fmaf(w01, A.w, fmaf(w00, A.z, bias)))), 0.f);
    const float t3 = fmaxf(fmaf(w11, m4,  fmaf(w10, M.w, fmaf(w01, a4,  fmaf(w00, A.w, bias)))), 0.f);
    const float u0 = fmaxf(fmaf(w11, Z.y, fmaf(w10, Z.x, fmaf(w01, M.y, fmaf(w00, M.x, bias)))), 0.f);
    const float u1 = fmaxf(fmaf(w11, Z.z, fmaf(w10, Z.y, fmaf(w01, M.z, fmaf(w00, M.y, bias)))), 0.f);
    const float u2 = fmaxf(fmaf(w11, Z.w, fmaf(w10, Z.z, fmaf(w01, M.w, fmaf(w00, M.z, bias)))), 0.f);
    const float u3 = fmaxf(fmaf(w11, z4,  fmaf(w10, Z.w, fmaf(w01, m4,  fmaf(w00, M.w, bias)))), 0.f);

    // qmap per 2x2 patch: cos(TL)*cos(TR)*cos(BR)
    const float q0 = __cosf(t0) * __cosf(t1) * __cosf(u1);
    const float q1 = __cosf(t2) * __cosf(t3) * __cosf(u3);

    const int r0 = r_base + 2 * il;
    const size_t o_off = (size_t)b * 2 * OH * OW + (size_t)r0 * OW + c0;
    float* __restrict__ o0 = out + o_off;
    float* __restrict__ o1 = o0 + OH * OW;

    // real output stores (identical to R7)
    store_nt4(o0,      t0, t1, t2, t3);
    store_nt4(o0 + OW, u0, u1, u2, u3);
    store_nt4(o1,      q0, q0, q1, q1);
    store_nt4(o1 + OW, q0, q0, q1, q1);

    // ---- DIAGNOSTIC traffic: reps replicas of out into the workspace ----
    for (int rp = 0; rp < reps; ++rp) {
        float* __restrict__ w0 = ws + (size_t)rp * OUTFLOATS + o_off;
        store_nt4(w0,               t0, t1, t2, t3);
        store_nt4(w0 + OW,          u0, u1, u2, u3);
        store_nt4(w0 + OH * OW,      q0, q0, q1, q1);
        store_nt4(w0 + OH * OW + OW, q0, q0, q1, q1);
    }
}

extern "C" void kernel_launch(void* const* d_in, const int* in_sizes, int n_in,
                              void* d_out, int out_size, void* d_ws, size_t ws_size,
                              hipStream_t stream)
{
    const float* x  = (const float*)d_in[0];
    const float* cw = (const float*)d_in[1];
    const float* cb = (const float*)d_in[2];
    // d_in[3] (qparams) provably does not affect the output.
    float* out = (float*)d_out;

    // replica count that fits the workspace (expect 8: ws = 256 MiB = 8x out)
    const size_t out_bytes = OUTFLOATS * sizeof(float);
    int reps = (int)(ws_size / out_bytes);
    if (reps > 8) reps = 8;

    const int grid  = BATCH * RG;   // 2048 blocks
    const int block = 256;
    conv_enh_diag<<<grid, block, 0, stream>>>(x, cw, cb, out, (float*)d_ws, reps);
}

// Round 9
// 78.731 us; speedup vs baseline: 1.5820x; 1.5820x over previous
//
#include <hip/hip_runtime.h>

// Problem: x [64,1,257,257] f32, conv_w [1,1,2,2], conv_b [1], qparams [2,4].
// Output [64,2,256,256] f32 = concat(conv-relu, qmap) on channel axis.
//
// Analytic collapse (re-derived R2; harness-verified, absmax 0.0625):
//   - qparams provably irrelevant; qmap per patch = cos(TL)*cos(TR)*cos(BR).
//
// Measurement state after R8 diagnostic (kernel's own counter row obtained by
// appending 8x replica writes to d_ws):
//   - base kernel window ~19.4 us for ~43 MB HBM (2.2 TB/s effective) while
//     the SAME memory system does 6.0 TB/s marginal on the appended writes.
//   - FETCH 9.4 MB < 16.9 MB input => L3 retains x across iterations.
//   - VALUBusy 2%, bank conflicts nil, time-avg occupancy 41%.
//   => kernel window is phase-serialized + ramp-dominated, NOT BW-bound.
//     (Explains R2==R5==R7 score insensitivity to load-path structure.)
//   - Score decomposition: fill ~47 + kernel ~19 + restores/gaps ~13 = ~79.8.
//
// R9 design: persistent blocks + double-buffered LDS staging.
//   512 blocks x 256 thr; each block pipelines 4 row-groups of one image:
//   issue reg-loads for tile g+1 -> compute+store tile g from LDS ->
//   ds_write tile g+1 -> barrier. Reads overlap writes; 4x block lifetime
//   amortizes ramp/drain. Traffic identical to R7; pure schedule change.
// R10 (this round): RESUBMIT unchanged — R8 GPU acquisition timeout; R9 is
//   unbenched, no unverified changes stacked. Predict score 72-76 if the
//   window-serialization theory is right; ~80 if residual is external (then
//   declare structural ceiling with the decomposition).

#define BATCH 64
#define INH   257
#define INW   257
#define OH    256
#define OW    256
#define LROWS 9             // input rows per tile (8 + 1 halo)
#define LPITCH 264          // LDS row pitch in floats (multiple of 4, padded)
#define GPB   4             // row-groups (tiles) per block
#define MACROS 8            // macro-groups per image: 8 * 32 rows = 256

typedef float fvec4 __attribute__((ext_vector_type(4)));

__device__ __forceinline__ void store_nt4(float* p, float x, float y, float z, float w)
{
    fvec4 v; v.x = x; v.y = y; v.z = z; v.w = w;
    __builtin_nontemporal_store(v, (fvec4*)p);
}

__global__ __launch_bounds__(256) void conv_enh_pipe(
    const float* __restrict__ x,
    const float* __restrict__ cw,
    const float* __restrict__ cb,
    float* __restrict__ out)
{
    __shared__ float lds[2][LROWS * LPITCH];   // 2 x 9504 B

    const int tid = threadIdx.x;
    const int blk = blockIdx.x;
    const int m   = blk & (MACROS - 1);        // 0..7 -> input rows 32m..32m+32
    const int b   = blk >> 3;                  // 0..63

    // uniform weight/bias loads first: latency hides under the prologue stage
    const float w00 = cw[0], w01 = cw[1], w10 = cw[2], w11 = cw[3];
    const float bias = cb[0];

    const float* __restrict__ img = x + (size_t)b * INH * INW;
    const int j  = tid & 63;                   // 0..63 -> output cols 4j..4j+3
    const int il = tid >> 6;                   // 0..3  -> local row-pair
    const int c0 = 4 * j;

    // ---- prologue: stage tile 0 directly into lds[0] ----
    {
        const float* __restrict__ s = img + (size_t)(m * 32) * INW;
        #pragma unroll
        for (int r = 0; r < LROWS; ++r)
            lds[0][r * LPITCH + tid] = s[r * INW + tid];
        if (tid < LROWS)
            lds[0][tid * LPITCH + 256] = s[tid * INW + 256];
    }
    __syncthreads();

    float reg[LROWS];
    float rhalo = 0.f;

    #pragma unroll
    for (int g = 0; g < GPB; ++g) {
        // issue next tile's global loads (in flight during compute+stores)
        if (g + 1 < GPB) {
            const float* __restrict__ s = img + (size_t)(m * 32 + (g + 1) * 8) * INW;
            #pragma unroll
            for (int r = 0; r < LROWS; ++r)
                reg[r] = s[r * INW + tid];
            rhalo = (tid < LROWS) ? s[tid * INW + 256] : 0.f;
        }

        // ---- compute tile g from lds[g&1] ----
        const float* __restrict__ l0 = &lds[g & 1][(2 * il) * LPITCH + c0];
        const float* __restrict__ l1 = l0 + LPITCH;
        const float* __restrict__ l2 = l1 + LPITCH;

        const fvec4 A = *(const fvec4*)l0;  const float a4 = l0[4];
        const fvec4 M = *(const fvec4*)l1;  const float m4 = l1[4];
        const fvec4 Z = *(const fvec4*)l2;  const float z4 = l2[4];

        const float t0 = fmaxf(fmaf(w11, M.y, fmaf(w10, M.x, fmaf(w01, A.y, fmaf(w00, A.x, bias)))), 0.f);
        const float t1 = fmaxf(fmaf(w11, M.z, fmaf(w10, M.y, fmaf(w01, A.z, fmaf(w00, A.y, bias)))), 0.f);
        const float t2 = fmaxf(fmaf(w11, M.w, fmaf(w10, M.z, fmaf(w01, A.w, fmaf(w00, A.z, bias)))), 0.f);
        const float t3 = fmaxf(fmaf(w11, m4,  fmaf(w10, M.w, fmaf(w01, a4,  fmaf(w00, A.w, bias)))), 0.f);
        const float u0 = fmaxf(fmaf(w11, Z.y, fmaf(w10, Z.x, fmaf(w01, M.y, fmaf(w00, M.x, bias)))), 0.f);
        const float u1 = fmaxf(fmaf(w11, Z.z, fmaf(w10, Z.y, fmaf(w01, M.z, fmaf(w00, M.y, bias)))), 0.f);
        const float u2 = fmaxf(fmaf(w11, Z.w, fmaf(w10, Z.z, fmaf(w01, M.w, fmaf(w00, M.z, bias)))), 0.f);
        const float u3 = fmaxf(fmaf(w11, z4,  fmaf(w10, Z.w, fmaf(w01, m4,  fmaf(w00, M.w, bias)))), 0.f);

        const float q0 = __cosf(t0) * __cosf(t1) * __cosf(u1);
        const float q1 = __cosf(t2) * __cosf(t3) * __cosf(u3);

        const int r0 = m * 32 + g * 8 + 2 * il;
        float* __restrict__ o0 = out + (size_t)b * 2 * OH * OW + (size_t)r0 * OW + c0;
        float* __restrict__ o1 = o0 + OH * OW;

        store_nt4(o0,      t0, t1, t2, t3);
        store_nt4(o0 + OW, u0, u1, u2, u3);
        store_nt4(o1,      q0, q0, q1, q1);
        store_nt4(o1 + OW, q0, q0, q1, q1);

        // ---- write next tile into the other LDS buffer, one barrier/tile ----
        if (g + 1 < GPB) {
            float* __restrict__ d = lds[(g + 1) & 1];
            #pragma unroll
            for (int r = 0; r < LROWS; ++r)
                d[r * LPITCH + tid] = reg[r];
            if (tid < LROWS)
                d[tid * LPITCH + 256] = rhalo;
            __syncthreads();
        }
    }
}

extern "C" void kernel_launch(void* const* d_in, const int* in_sizes, int n_in,
                              void* d_out, int out_size, void* d_ws, size_t ws_size,
                              hipStream_t stream)
{
    const float* x  = (const float*)d_in[0];
    const float* cw = (const float*)d_in[1];
    const float* cb = (const float*)d_in[2];
    // d_in[3] (qparams) provably does not affect the output.
    float* out = (float*)d_out;

    const int grid  = BATCH * MACROS;   // 512 blocks, 4 tiles each
    const int block = 256;
    conv_enh_pipe<<<grid, block, 0, stream>>>(x, cw, cb, out);
}